// Round 1
// baseline (5733.669 us; speedup 1.0000x reference)
//
#include <hip/hip_runtime.h>
#include <hip/hip_bf16.h>

// Leaky tanh RNN, persistent cooperative kernel.
// h_{t+1} = 0.9 h_t + 0.1 (x_t@wi + tanh(h_t)@wrec + 0.02 n_t); out_t = tanh(h_{t+1})@wo
//
// Decomposition: 2 batch-groups x 32 batches. Per group: 32 "h" WGs each own a
// 32-column slice of wrec (split-precision bf16 hi+lo, LDS-resident) and the
// corresponding h[32batch,32col] slice in registers (MFMA C-frag layout);
// 2 "o" WGs own 32-column slices of wo and emit out (lagged one step).
// g = tanh(h) is broadcast through a double-buffered global bf16 buffer with a
// per-group atomic-counter barrier each step.

#define T_ 512
#define I_ 128
#define H_ 1024
#define O_ 64

#define GRPS 2
#define BG 32
#define SLICE 32
#define HWGS (H_/SLICE)      // 32
#define OWGS (O_/SLICE)      // 2
#define WGPG (HWGS+OWGS)     // 34
#define NWG (GRPS*WGPG)      // 68

// LDS layout (elements of __bf16)
#define WHI_OFF 0
#define WLO_OFF (H_*SLICE)
#define WIHI_OFF (2*H_*SLICE)
#define WILO_OFF (2*H_*SLICE + I_*SLICE)
#define LDS_ELEMS (2*H_*SLICE + 2*I_*SLICE)  // 73728
#define LDS_BYTES (LDS_ELEMS*2)              // 147456

#define GBUF_BYTES (GRPS*2*BG*H_*2)          // 262144

typedef __bf16 bf16x8 __attribute__((ext_vector_type(8)));
typedef float f32x4 __attribute__((ext_vector_type(4)));

__device__ __forceinline__ float fast_tanh(float v){
  float cx = fminf(fmaxf(v, -14.f), 14.f);
  float e = __builtin_amdgcn_exp2f(cx * 2.8853900817779268f); // exp(2x)
  return 1.f - 2.f * __builtin_amdgcn_rcpf(e + 1.f);
}

// Load a [K x 32] column-slice of a row-major [K x ld] fp32 matrix into LDS as
// split-precision bf16 (hi + lo), pre-swizzled into MFMA B-fragment order:
// lane l of tile (kt,ntile) holds B[kt*32 + (l>>4)*8 + j][ntile*16 + (l&15)].
__device__ void load_slice(const float* __restrict__ Wg, int ld, int c0, int K,
                           __bf16* hi, __bf16* lo){
  for (int idx = threadIdx.x; idx < K*SLICE; idx += 256){
    int k = idx >> 5, c = idx & 31;
    float v = Wg[(size_t)k*ld + c0 + c];
    __bf16 h = (__bf16)v;
    __bf16 l = (__bf16)(v - (float)h);
    int kt = k >> 5, kin = k & 31, lg = kin >> 3, j = kin & 7;
    int off = (((kt*2 + (c>>4))*64 + (lg*16 + (c&15))) << 3) + j;
    hi[off] = h; lo[off] = l;
  }
}

extern "C" __global__ __launch_bounds__(256, 1)
void rnn_step_kernel(const float* __restrict__ x, const float* __restrict__ noise,
                     const float* __restrict__ wi, const float* __restrict__ wrec,
                     const float* __restrict__ wo, float* __restrict__ out,
                     unsigned short* __restrict__ gbuf, unsigned* __restrict__ ctrs)
{
  extern __shared__ __bf16 lds[];
  const int bid  = blockIdx.x;
  const int grp  = bid / WGPG;
  const int role = bid % WGPG;
  const bool is_h = (role < HWGS);
  const int c0 = is_h ? role*SLICE : (role - HWGS)*SLICE;

  if (is_h){
    load_slice(wrec, H_, c0, H_, lds + WHI_OFF, lds + WLO_OFF);
    load_slice(wi,   H_, c0, I_, lds + WIHI_OFF, lds + WILO_OFF);
  } else {
    load_slice(wo,   O_, c0, H_, lds + WHI_OFF, lds + WLO_OFF);
  }
  __syncthreads();

  const int lane = threadIdx.x & 63;
  const int wave = threadIdx.x >> 6;   // 4 waves: (mtile, ntile) = (wave>>1, wave&1)
  const int mt = wave >> 1, nt = wave & 1;
  const int arow = mt*16 + (lane & 15);   // A-frag row (local batch)
  const int kg   = lane >> 4;             // k-group 0..3
  const int crow = mt*16 + kg*4;          // C-frag rows (local batch) + r
  const int ccol = nt*16 + (lane & 15);   // C-frag col (within slice)

  unsigned short* g0 = gbuf + (size_t)grp*(2*BG*H_);
  unsigned* ctr = ctrs + grp*64;

  f32x4 hreg = {0.f, 0.f, 0.f, 0.f};
  const int bfoff = nt*512 + lane*8;

  for (int i = 0; i <= T_; ++i){
    const bool active = is_h ? (i < T_) : (i >= 1);
    if (active){
      const int tstep = is_h ? i : (i - 1);
      f32x4 accA = {0.f,0.f,0.f,0.f}, accB = {0.f,0.f,0.f,0.f};

      if (is_h){
        // x_t @ wi : 3-pass split (x_hi*wi_hi -> A, x_lo*wi_hi -> B, x_hi*wi_lo -> A)
        const float* xp = x + (size_t)(grp*BG + arow)*T_*I_ + (size_t)tstep*I_ + kg*8;
        #pragma unroll
        for (int kt = 0; kt < I_/32; ++kt){
          f32x4 v0 = *(const f32x4*)(xp + kt*32);
          f32x4 v1 = *(const f32x4*)(xp + kt*32 + 4);
          bf16x8 xh, xl;
          #pragma unroll
          for (int j = 0; j < 4; ++j){
            float a = v0[j], b = v1[j];
            __bf16 ah = (__bf16)a, bh = (__bf16)b;
            xh[j]   = ah;                       xh[j+4] = bh;
            xl[j]   = (__bf16)(a - (float)ah);  xl[j+4] = (__bf16)(b - (float)bh);
          }
          bf16x8 wih = *(const bf16x8*)(lds + WIHI_OFF + kt*1024 + bfoff);
          bf16x8 wil = *(const bf16x8*)(lds + WILO_OFF + kt*1024 + bfoff);
          accA = __builtin_amdgcn_mfma_f32_16x16x32_bf16(xh, wih, accA, 0,0,0);
          accB = __builtin_amdgcn_mfma_f32_16x16x32_bf16(xl, wih, accB, 0,0,0);
          accA = __builtin_amdgcn_mfma_f32_16x16x32_bf16(xh, wil, accA, 0,0,0);
        }
      }

      { // g_i @ Wslice : 2-pass split weights
        const unsigned short* gcur = g0 + (size_t)(i&1)*BG*H_;
        const unsigned short* aptr = gcur + (size_t)arow*H_ + kg*8;
        #pragma unroll 8
        for (int kt = 0; kt < H_/32; ++kt){
          bf16x8 a  = *(const bf16x8*)(aptr + kt*32);
          bf16x8 bh = *(const bf16x8*)(lds + WHI_OFF + kt*1024 + bfoff);
          bf16x8 bl = *(const bf16x8*)(lds + WLO_OFF + kt*1024 + bfoff);
          accA = __builtin_amdgcn_mfma_f32_16x16x32_bf16(a, bh, accA, 0,0,0);
          accB = __builtin_amdgcn_mfma_f32_16x16x32_bf16(a, bl, accB, 0,0,0);
        }
      }

      if (is_h){
        unsigned short* gnext = g0 + (size_t)((i+1)&1)*BG*H_;
        #pragma unroll
        for (int r = 0; r < 4; ++r){
          float nv = noise[(size_t)(grp*BG + crow + r)*T_*H_ + (size_t)tstep*H_ + c0 + ccol];
          float h = 0.9f*hreg[r] + 0.1f*(accA[r] + accB[r]) + 0.002f*nv;
          hreg[r] = h;
          float g = fast_tanh(h);
          gnext[(size_t)(crow + r)*H_ + c0 + ccol] = __builtin_bit_cast(unsigned short, (__bf16)g);
        }
      } else {
        #pragma unroll
        for (int r = 0; r < 4; ++r){
          out[(size_t)(grp*BG + crow + r)*T_*O_ + (size_t)tstep*O_ + c0 + ccol] = accA[r] + accB[r];
        }
      }
    }

    if (i < T_){
      // per-group bulk-sync barrier: publish g_{i+1}, wait for all 34 WGs
      __syncthreads();
      if (threadIdx.x == 0){
        __threadfence();
        __hip_atomic_fetch_add(ctr, 1u, __ATOMIC_RELEASE, __HIP_MEMORY_SCOPE_AGENT);
        const unsigned tgt = (unsigned)(WGPG*(i+1));
        while (__hip_atomic_load(ctr, __ATOMIC_RELAXED, __HIP_MEMORY_SCOPE_AGENT) < tgt)
          __builtin_amdgcn_s_sleep(2);
        __threadfence();
      }
      __syncthreads();
    }
  }
}

extern "C" void kernel_launch(void* const* d_in, const int* in_sizes, int n_in,
                              void* d_out, int out_size, void* d_ws, size_t ws_size,
                              hipStream_t stream){
  const float* x     = (const float*)d_in[0];
  const float* noise = (const float*)d_in[1];
  const float* wi    = (const float*)d_in[2];
  const float* wrec  = (const float*)d_in[3];
  const float* wo    = (const float*)d_in[4];
  float* out = (float*)d_out;

  if (ws_size < (size_t)(GBUF_BYTES + 1024)) return;
  unsigned short* gbuf = (unsigned short*)d_ws;
  unsigned* ctrs = (unsigned*)((char*)d_ws + GBUF_BYTES);

  // zero g_0 and the barrier counters (graph-capturable async memset)
  hipMemsetAsync(d_ws, 0, GBUF_BYTES + 1024, stream);

  hipFuncSetAttribute((const void*)rnn_step_kernel,
                      hipFuncAttributeMaxDynamicSharedMemorySize, LDS_BYTES);

  void* args[] = {(void*)&x, (void*)&noise, (void*)&wi, (void*)&wrec, (void*)&wo,
                  (void*)&out, (void*)&gbuf, (void*)&ctrs};
  hipLaunchCooperativeKernel((const void*)rnn_step_kernel, dim3(NWG), dim3(256),
                             args, LDS_BYTES, stream);
}

// Round 2
// 4831.335 us; speedup vs baseline: 1.1868x; 1.1868x over previous
//
#include <hip/hip_runtime.h>
#include <hip/hip_bf16.h>

// Leaky tanh RNN, persistent cooperative kernel (round 2: cheap barrier).
// h_{t+1} = 0.9 h_t + 0.1 (x_t@wi + tanh(h_t)@wrec + 0.02 n_t); out_t = tanh(h_{t+1})@wo
//
// 2 batch-groups x 32 batches. Per group: 32 "h" WGs own a 32-col slice of wrec
// (bf16 hi+lo split, LDS-resident) + h[32,32] in MFMA C-frag registers; 2 "o" WGs
// own 32-col slices of wo. g=tanh(h) broadcast via double-buffered global bf16
// buffer. Sync: per-WG flag words (coherent store + all-lane poll), no RMW, no
// L2 writeback fences. x@wi + noise prefetched into the wait shadow.

#define T_ 512
#define I_ 128
#define H_ 1024
#define O_ 64

#define GRPS 2
#define BG 32
#define SLICE 32
#define HWGS (H_/SLICE)      // 32
#define OWGS (O_/SLICE)      // 2
#define WGPG (HWGS+OWGS)     // 34
#define NWG (GRPS*WGPG)      // 68

// LDS layout (elements of __bf16)
#define WHI_OFF 0
#define WLO_OFF (H_*SLICE)
#define WIHI_OFF (2*H_*SLICE)
#define WILO_OFF (2*H_*SLICE + I_*SLICE)
#define LDS_ELEMS (2*H_*SLICE + 2*I_*SLICE)  // 73728
#define LDS_BYTES (LDS_ELEMS*2)              // 147456

#define GBUF_BYTES (GRPS*2*BG*H_*2)          // 262144
#define FLAG_STRIDE 64                        // dwords per group

typedef __bf16 bf16x8 __attribute__((ext_vector_type(8)));
typedef float f32x4 __attribute__((ext_vector_type(4)));

__device__ __forceinline__ float fast_tanh(float v){
  float cx = fminf(fmaxf(v, -14.f), 14.f);
  float e = __builtin_amdgcn_exp2f(cx * 2.8853900817779268f); // exp(2x)
  return 1.f - 2.f * __builtin_amdgcn_rcpf(e + 1.f);
}

// coherent (LLC-visible) 16-bit store: bypasses non-coherent L1/L2
__device__ __forceinline__ void store_u16_llc(unsigned short* p, unsigned v){
  asm volatile("global_store_short %0, %1, off sc0 sc1" :: "v"(p), "v"(v) : "memory");
}

// Load a [K x 32] column-slice of a row-major [K x ld] fp32 matrix into LDS as
// split-precision bf16 (hi + lo), pre-swizzled into MFMA B-fragment order.
__device__ void load_slice(const float* __restrict__ Wg, int ld, int c0, int K,
                           __bf16* hi, __bf16* lo){
  for (int idx = threadIdx.x; idx < K*SLICE; idx += 256){
    int k = idx >> 5, c = idx & 31;
    float v = Wg[(size_t)k*ld + c0 + c];
    __bf16 h = (__bf16)v;
    __bf16 l = (__bf16)(v - (float)h);
    int kt = k >> 5, kin = k & 31, lg = kin >> 3, j = kin & 7;
    int off = (((kt*2 + (c>>4))*64 + (lg*16 + (c&15))) << 3) + j;
    hi[off] = h; lo[off] = l;
  }
}

// x_{t}@wi fragment MFMAs + noise prefetch (independent of g -> hidden in wait shadow)
__device__ __forceinline__ void prefetch_step(const float* __restrict__ x,
                                              const float* __restrict__ noise,
                                              const __bf16* __restrict__ ldsp,
                                              int grp, int arow, int kg, int crow,
                                              int ccol, int c0, int bfoff, int tstep,
                                              f32x4& xA, f32x4& xB, float* nz){
  const float* xp = x + (size_t)(grp*BG + arow)*T_*I_ + (size_t)tstep*I_ + kg*8;
  #pragma unroll
  for (int kt = 0; kt < I_/32; ++kt){
    f32x4 v0 = *(const f32x4*)(xp + kt*32);
    f32x4 v1 = *(const f32x4*)(xp + kt*32 + 4);
    bf16x8 xh, xl;
    #pragma unroll
    for (int j = 0; j < 4; ++j){
      float a = v0[j], b = v1[j];
      __bf16 ah = (__bf16)a, bh = (__bf16)b;
      xh[j]   = ah;                       xh[j+4] = bh;
      xl[j]   = (__bf16)(a - (float)ah);  xl[j+4] = (__bf16)(b - (float)bh);
    }
    bf16x8 wih = *(const bf16x8*)(ldsp + WIHI_OFF + kt*1024 + bfoff);
    bf16x8 wil = *(const bf16x8*)(ldsp + WILO_OFF + kt*1024 + bfoff);
    xA = __builtin_amdgcn_mfma_f32_16x16x32_bf16(xh, wih, xA, 0,0,0);
    xB = __builtin_amdgcn_mfma_f32_16x16x32_bf16(xl, wih, xB, 0,0,0);
    xA = __builtin_amdgcn_mfma_f32_16x16x32_bf16(xh, wil, xA, 0,0,0);
  }
  #pragma unroll
  for (int r = 0; r < 4; ++r)
    nz[r] = noise[(size_t)(grp*BG + crow + r)*T_*H_ + (size_t)tstep*H_ + c0 + ccol];
}

extern "C" __global__ __launch_bounds__(256, 1)
void rnn_step_kernel(const float* __restrict__ x, const float* __restrict__ noise,
                     const float* __restrict__ wi, const float* __restrict__ wrec,
                     const float* __restrict__ wo, float* __restrict__ out,
                     unsigned short* __restrict__ gbuf, unsigned* __restrict__ flagbase)
{
  extern __shared__ __bf16 lds[];
  const int bid  = blockIdx.x;
  const int grp  = bid / WGPG;
  const int role = bid % WGPG;
  const bool is_h = (role < HWGS);
  const int c0 = is_h ? role*SLICE : (role - HWGS)*SLICE;

  if (is_h){
    load_slice(wrec, H_, c0, H_, lds + WHI_OFF, lds + WLO_OFF);
    load_slice(wi,   H_, c0, I_, lds + WIHI_OFF, lds + WILO_OFF);
  } else {
    load_slice(wo,   O_, c0, H_, lds + WHI_OFF, lds + WLO_OFF);
  }
  __syncthreads();

  const int lane = threadIdx.x & 63;
  const int wave = threadIdx.x >> 6;   // 4 waves: (mtile, ntile) = (wave>>1, wave&1)
  const int mt = wave >> 1, nt = wave & 1;
  const int arow = mt*16 + (lane & 15);   // A-frag row (local batch)
  const int kg   = lane >> 4;             // k-group 0..3
  const int crow = mt*16 + kg*4;          // C-frag rows (local batch) + r
  const int ccol = nt*16 + (lane & 15);   // C-frag col (within slice)
  const int bfoff = nt*512 + lane*8;

  unsigned short* g0 = gbuf + (size_t)grp*(2*BG*H_);
  unsigned* flags = flagbase + grp*FLAG_STRIDE;
  const unsigned* mypoll = flags + (lane < WGPG ? lane : 0);

  f32x4 hreg = {0.f, 0.f, 0.f, 0.f};
  f32x4 xA = {0.f,0.f,0.f,0.f}, xB = {0.f,0.f,0.f,0.f};
  float nz[4] = {0.f,0.f,0.f,0.f};

  if (is_h)
    prefetch_step(x, noise, lds, grp, arow, kg, crow, ccol, c0, bfoff, 0, xA, xB, nz);

  for (int i = 0; i <= T_; ++i){
    if (is_h && i == T_) break;   // h-WGs have no work at the tail step

    // ---- wait for all WGs in group to reach step i (g_i published) ----
    if (i > 0){
      const unsigned tgt = (unsigned)i;
      while (true){
        unsigned v = __hip_atomic_load(mypoll, __ATOMIC_RELAXED, __HIP_MEMORY_SCOPE_AGENT);
        if (__all((int)(v >= tgt))) break;
      }
      __builtin_amdgcn_fence(__ATOMIC_ACQUIRE, "agent");  // inv stale L1/L2 (cheap: reuse is in LDS/regs)
    }

    if (is_h){
      // ---- g_i @ wrec (2-pass split weights), seeded with prefetched x@wi ----
      f32x4 accA = xA, accB = xB;
      const unsigned short* gcur = g0 + (size_t)(i&1)*BG*H_;
      const unsigned short* aptr = gcur + (size_t)arow*H_ + kg*8;
      #pragma unroll 8
      for (int kt = 0; kt < H_/32; ++kt){
        bf16x8 a  = *(const bf16x8*)(aptr + kt*32);
        bf16x8 bh = *(const bf16x8*)(lds + WHI_OFF + kt*1024 + bfoff);
        bf16x8 bl = *(const bf16x8*)(lds + WLO_OFF + kt*1024 + bfoff);
        accA = __builtin_amdgcn_mfma_f32_16x16x32_bf16(a, bh, accA, 0,0,0);
        accB = __builtin_amdgcn_mfma_f32_16x16x32_bf16(a, bl, accB, 0,0,0);
      }

      // ---- h update + publish g_{i+1} (coherent stores) ----
      unsigned short* gnext = g0 + (size_t)((i+1)&1)*BG*H_;
      #pragma unroll
      for (int r = 0; r < 4; ++r){
        float h = 0.9f*hreg[r] + 0.1f*(accA[r] + accB[r]) + 0.002f*nz[r];
        hreg[r] = h;
        float g = fast_tanh(h);
        unsigned short u = __builtin_bit_cast(unsigned short, (__bf16)g);
        store_u16_llc(gnext + (size_t)(crow + r)*H_ + c0 + ccol, (unsigned)u);
      }
      asm volatile("s_waitcnt vmcnt(0)" ::: "memory");  // g stores at coherence point
      __syncthreads();                                  // all 4 waves done
      if (threadIdx.x == 0)
        __hip_atomic_store(flags + role, (unsigned)(i+1), __ATOMIC_RELAXED, __HIP_MEMORY_SCOPE_AGENT);

      // ---- prefetch next step's x@wi + noise into the wait shadow ----
      if (i + 1 < T_){
        xA = (f32x4){0.f,0.f,0.f,0.f}; xB = (f32x4){0.f,0.f,0.f,0.f};
        prefetch_step(x, noise, lds, grp, arow, kg, crow, ccol, c0, bfoff, i+1, xA, xB, nz);
      }
    } else {
      if (i == 0){
        if (threadIdx.x == 0)
          __hip_atomic_store(flags + role, 1u, __ATOMIC_RELAXED, __HIP_MEMORY_SCOPE_AGENT);
        continue;
      }
      // ---- out_{i-1} = g_i @ wo (2-pass split) ----
      f32x4 accA = {0.f,0.f,0.f,0.f}, accB = {0.f,0.f,0.f,0.f};
      const unsigned short* gcur = g0 + (size_t)(i&1)*BG*H_;
      const unsigned short* aptr = gcur + (size_t)arow*H_ + kg*8;
      #pragma unroll 8
      for (int kt = 0; kt < H_/32; ++kt){
        bf16x8 a  = *(const bf16x8*)(aptr + kt*32);
        bf16x8 bh = *(const bf16x8*)(lds + WHI_OFF + kt*1024 + bfoff);
        bf16x8 bl = *(const bf16x8*)(lds + WLO_OFF + kt*1024 + bfoff);
        accA = __builtin_amdgcn_mfma_f32_16x16x32_bf16(a, bh, accA, 0,0,0);
        accB = __builtin_amdgcn_mfma_f32_16x16x32_bf16(a, bl, accB, 0,0,0);
      }
      #pragma unroll
      for (int r = 0; r < 4; ++r)
        out[(size_t)(grp*BG + crow + r)*T_*O_ + (size_t)(i-1)*O_ + c0 + ccol] = accA[r] + accB[r];

      if (i < T_){
        asm volatile("s_waitcnt vmcnt(0)" ::: "memory");  // g_i reads fully retired
        __syncthreads();
        if (threadIdx.x == 0)
          __hip_atomic_store(flags + role, (unsigned)(i+1), __ATOMIC_RELAXED, __HIP_MEMORY_SCOPE_AGENT);
      }
    }
  }
}

extern "C" void kernel_launch(void* const* d_in, const int* in_sizes, int n_in,
                              void* d_out, int out_size, void* d_ws, size_t ws_size,
                              hipStream_t stream){
  const float* x     = (const float*)d_in[0];
  const float* noise = (const float*)d_in[1];
  const float* wi    = (const float*)d_in[2];
  const float* wrec  = (const float*)d_in[3];
  const float* wo    = (const float*)d_in[4];
  float* out = (float*)d_out;

  if (ws_size < (size_t)(GBUF_BYTES + 1024)) return;
  unsigned short* gbuf = (unsigned short*)d_ws;
  unsigned* flags = (unsigned*)((char*)d_ws + GBUF_BYTES);

  // zero g_0 and the flag words (graph-capturable async memset)
  hipMemsetAsync(d_ws, 0, GBUF_BYTES + 1024, stream);

  hipFuncSetAttribute((const void*)rnn_step_kernel,
                      hipFuncAttributeMaxDynamicSharedMemorySize, LDS_BYTES);

  void* args[] = {(void*)&x, (void*)&noise, (void*)&wi, (void*)&wrec, (void*)&wo,
                  (void*)&out, (void*)&gbuf, (void*)&flags};
  hipLaunchCooperativeKernel((const void*)rnn_step_kernel, dim3(NWG), dim3(256),
                             args, LDS_BYTES, stream);
}

// Round 5
// 3348.576 us; speedup vs baseline: 1.7123x; 1.4428x over previous
//
#include <hip/hip_runtime.h>
#include <hip/hip_bf16.h>

// Leaky tanh RNN, persistent cooperative kernel (round 5: system-scope comm,
// no fences, no cache invalidation — bisects R4's failure).
// 8 groups x 8 batches, grp = blockIdx>>5 (no XCD claim). Per group: 32 WGs;
// WG role r owns wrec[:, 32r:32r+32] (bf16 hi+lo, LDS), wi[:, slice], wo 2 cols.
// K split across the WG's 4 waves, cross-wave LDS reduce.
// All g/flag traffic uses sc0 sc1 (system scope -> MALL coherence point) on
// BOTH producer and consumer sides: visibility chain is
//   g stores (sc0 sc1) -> vmcnt(0) -> flag store (sc0 sc1)
//   flag poll (sc0 sc1) -> g loads (sc0 sc1)
// so no fence / buffer_inv is needed and x/noise/weights stay cached.

#define T_ 512
#define I_ 128
#define H_ 1024
#define O_ 64
#define GRPS 8
#define BG 8             // batches per group
#define WPG 32           // WGs per group
#define NWG 256
#define POLL_CAP (1<<17)

// workspace layout
#define GBUF_ELEMS (GRPS*2*BG*H_)       // 131072 bf16
#define GBUF_BYTES (GBUF_ELEMS*2)       // 262144
#define STEPFLAG_OFF GBUF_BYTES         // u16[8][32] = 512 B
#define WS_NEED (GBUF_BYTES + 1024)

// LDS layout
#define WREC_HI_E 0
#define WREC_LO_E 32768
#define WI_HI_E   65536
#define WI_LO_E   69632
#define WO_HI_E   73728      // col-major [2][1024]
#define WO_LO_E   75776
#define RED_OFF_B   155648   // 9 slots * 32 lanes * 16B = 4608
#define NOISE_OFF_B 160256   // 8*32 f32 = 1024
#define LDS_BYTES   161280

typedef __bf16 bf16x8 __attribute__((ext_vector_type(8)));
typedef float f32x4 __attribute__((ext_vector_type(4)));
typedef unsigned u32x4 __attribute__((ext_vector_type(4)));
typedef unsigned short u16;

__device__ __forceinline__ float fast_tanh(float v){
  float cx = fminf(fmaxf(v, -14.f), 14.f);
  float e = __builtin_amdgcn_exp2f(cx * 2.8853900817779268f); // exp(2x)
  return 1.f - 2.f * __builtin_amdgcn_rcpf(e + 1.f);
}

__device__ __forceinline__ unsigned sflag_load(const u16* p){
  unsigned v;
  asm volatile("global_load_ushort %0, %1, off sc0 sc1\n\ts_waitcnt vmcnt(0)"
               : "=v"(v) : "v"(p) : "memory");
  return v;
}
__device__ __forceinline__ void sflag_store(u16* p, unsigned v){
  asm volatile("global_store_short %0, %1, off sc0 sc1" :: "v"(p), "v"(v) : "memory");
}
__device__ __forceinline__ void g_load_frag(u32x4& d, const u16* p){
  asm volatile("global_load_dwordx4 %0, %1, off sc0 sc1" : "=v"(d) : "v"(p) : "memory");
}
__device__ __forceinline__ void g_store_u16(u16* p, unsigned v){
  asm volatile("global_store_short %0, %1, off sc0 sc1" :: "v"(p), "v"(v) : "memory");
}

// [K x 32] col-slice of row-major [K x ld] fp32 -> LDS split bf16 (hi+lo),
// pre-swizzled into MFMA B-frag order (verified rounds 1-2).
__device__ void load_slice(const float* __restrict__ Wg, int ld, int c0, int K,
                           __bf16* hi, __bf16* lo){
  for (int idx = threadIdx.x; idx < K*32; idx += 256){
    int k = idx >> 5, c = idx & 31;
    float v = Wg[(size_t)k*ld + c0 + c];
    __bf16 h = (__bf16)v;
    __bf16 l = (__bf16)(v - (float)h);
    int kt = k >> 5, kin = k & 31, lg = kin >> 3, j = kin & 7;
    int off = (((kt*2 + (c>>4))*64 + (lg*16 + (c&15))) << 3) + j;
    hi[off] = h; lo[off] = l;
  }
}

#define MFMA __builtin_amdgcn_mfma_f32_16x16x32_bf16
#define BC(u) __builtin_bit_cast(bf16x8, u)

extern "C" __global__ __launch_bounds__(256, 1)
void rnn_kernel(const float* __restrict__ x, const float* __restrict__ noise,
                const float* __restrict__ wi, const float* __restrict__ wrec,
                const float* __restrict__ wo, float* __restrict__ out,
                u16* __restrict__ gbuf, u16* __restrict__ sflags)
{
  extern __shared__ char smem[];
  __bf16* B = (__bf16*)smem;
  float* RED = (float*)(smem + RED_OFF_B);
  float* NS  = (float*)(smem + NOISE_OFF_B);

  const int grp  = blockIdx.x >> 5;
  const int role = blockIdx.x & 31;
  const int c0 = role * 32;

  load_slice(wrec, H_, c0, H_, B + WREC_HI_E, B + WREC_LO_E);
  load_slice(wi,   H_, c0, I_, B + WI_HI_E,  B + WI_LO_E);
  for (int idx = threadIdx.x; idx < 2*H_; idx += 256){
    int col = idx >> 10, k = idx & (H_-1);
    float v = wo[(size_t)k*O_ + role*2 + col];
    __bf16 hh = (__bf16)v;
    B[WO_HI_E + col*H_ + k] = hh;
    B[WO_LO_E + col*H_ + k] = (__bf16)(v - (float)hh);
  }
  __syncthreads();

  const int lane = threadIdx.x & 63;
  const int w    = threadIdx.x >> 6;   // wave = k-chunk (256 k each)
  const int lhalf = lane >> 4;         // 0..3
  const int l15   = lane & 15;
  const int bf = lane * 8;

  u16* gg = gbuf + grp * (2*BG*H_);
  u16* gf = sflags + grp * 32;
  const u16* pollp = gf + (lane & 31);
  u16* myflag = gf + role;
  const u16* abase = gg + (size_t)(lane & 7)*H_ + w*256 + lhalf*8;
  const int wo_off = (l15 & 1)*1024 + lhalf*8;

  f32x4 h0 = {0.f,0.f,0.f,0.f};        // w0: rows for cols 0-15, w1: cols 16-31 (lanes<32)
  f32x4 xA = {0.f,0.f,0.f,0.f}, xB = {0.f,0.f,0.f,0.f};

  for (int i = 0; i < T_; ++i){
    // ---------- shadow work (independent of g_i): x@wi (w0,w1), noise (w3) ----------
    if (w < 2){
      xA = (f32x4){0.f,0.f,0.f,0.f}; xB = (f32x4){0.f,0.f,0.f,0.f};
      const float* xp = x + ((size_t)(grp*BG + (l15 & 7))*T_ + i)*I_ + lhalf*8;
      #pragma unroll
      for (int kt = 0; kt < 4; ++kt){
        f32x4 v0 = *(const f32x4*)(xp + kt*32);
        f32x4 v1 = *(const f32x4*)(xp + kt*32 + 4);
        bf16x8 xh, xl;
        #pragma unroll
        for (int j = 0; j < 4; ++j){
          float a = v0[j], b2 = v1[j];
          __bf16 ah = (__bf16)a, bh2 = (__bf16)b2;
          xh[j] = ah; xh[j+4] = bh2;
          xl[j] = (__bf16)(a - (float)ah); xl[j+4] = (__bf16)(b2 - (float)bh2);
        }
        bf16x8 wih = *(const bf16x8*)(B + WI_HI_E + kt*1024 + w*512 + bf);
        bf16x8 wil = *(const bf16x8*)(B + WI_LO_E + kt*1024 + w*512 + bf);
        xA = MFMA(xh, wih, xA, 0,0,0);
        xB = MFMA(xl, wih, xB, 0,0,0);
        xA = MFMA(xh, wil, xA, 0,0,0);
      }
    } else if (w == 3){
      #pragma unroll
      for (int q = 0; q < 4; ++q){
        int b = (lane>>5) + q*2, c = lane & 31;
        NS[b*32 + c] = noise[((size_t)(grp*BG + b)*T_ + i)*H_ + c0 + c];
      }
    }

    // ---------- wait for g_i published (bounded poll) ----------
    if (i > 0){
      const unsigned tgt = (unsigned)i;
      int guard = 0;
      while (true){
        unsigned v = sflag_load(pollp);
        if (__all((int)(v >= tgt))) break;
        if (++guard > POLL_CAP) break;   // bail: wrong answer beats a hang
      }
    }

    // ---------- A-frags: this wave's k-chunk of g_i (system-scope loads) ----------
    const u16* ap = abase + (size_t)(i & 1)*BG*H_;
    u32x4 a[8];
    #pragma unroll
    for (int kt = 0; kt < 8; ++kt) g_load_frag(a[kt], ap + kt*32);
    asm volatile("s_waitcnt vmcnt(0)"
      : "+v"(a[0]),"+v"(a[1]),"+v"(a[2]),"+v"(a[3]),
        "+v"(a[4]),"+v"(a[5]),"+v"(a[6]),"+v"(a[7]));
    __builtin_amdgcn_sched_barrier(0);

    // ---------- MFMAs: wrec nt0/nt1 (hi+lo) + wo (hi+lo) ----------
    f32x4 c0A={0.f,0.f,0.f,0.f}, c0B={0.f,0.f,0.f,0.f};
    f32x4 c1A={0.f,0.f,0.f,0.f}, c1B={0.f,0.f,0.f,0.f};
    f32x4 oA ={0.f,0.f,0.f,0.f}, oB ={0.f,0.f,0.f,0.f};
    if (w == 0){ c0A = xA; c0B = xB; }
    if (w == 1){ c1A = xA; c1B = xB; }
    const int kb = w*8;
    #pragma unroll
    for (int kt = 0; kt < 8; ++kt){
      const int kg = kb + kt;
      bf16x8 bh0 = *(const bf16x8*)(B + WREC_HI_E + kg*1024 + bf);
      bf16x8 bl0 = *(const bf16x8*)(B + WREC_LO_E + kg*1024 + bf);
      bf16x8 bh1 = *(const bf16x8*)(B + WREC_HI_E + kg*1024 + 512 + bf);
      bf16x8 bl1 = *(const bf16x8*)(B + WREC_LO_E + kg*1024 + 512 + bf);
      bf16x8 wh  = *(const bf16x8*)(B + WO_HI_E + wo_off + kg*32);
      bf16x8 wl  = *(const bf16x8*)(B + WO_LO_E + wo_off + kg*32);
      bf16x8 av = BC(a[kt]);
      c0A = MFMA(av, bh0, c0A, 0,0,0);  c0B = MFMA(av, bl0, c0B, 0,0,0);
      c1A = MFMA(av, bh1, c1A, 0,0,0);  c1B = MFMA(av, bl1, c1B, 0,0,0);
      oA  = MFMA(av, wh,  oA,  0,0,0);  oB  = MFMA(av, wl,  oB,  0,0,0);
    }
    f32x4 cn0 = c0A + c0B, cn1 = c1A + c1B, co = oA + oB;

    // ---------- cross-wave reduce (rows 0-7 live in lanes 0-31) ----------
    if (lane < 32){
      if (w == 0){ *(f32x4*)&RED[((1*3+0)*32+lane)*4] = cn1; *(f32x4*)&RED[((2*3+0)*32+lane)*4] = co; }
      if (w == 1){ *(f32x4*)&RED[((0*3+0)*32+lane)*4] = cn0; *(f32x4*)&RED[((2*3+1)*32+lane)*4] = co; }
      if (w == 2){ *(f32x4*)&RED[((0*3+1)*32+lane)*4] = cn0; *(f32x4*)&RED[((1*3+1)*32+lane)*4] = cn1; }
      if (w == 3){ *(f32x4*)&RED[((0*3+2)*32+lane)*4] = cn0; *(f32x4*)&RED[((1*3+2)*32+lane)*4] = cn1; *(f32x4*)&RED[((2*3+2)*32+lane)*4] = co; }
    }
    __syncthreads();

    if (w < 2 && lane < 32){
      // owner of col-half w: total = own + 3 partials; h update + publish g_{i+1}
      const int fbase = w ? 1*3 : 0*3;
      f32x4 s = w ? cn1 : cn0;
      s += *(f32x4*)&RED[((fbase+0)*32+lane)*4];
      s += *(f32x4*)&RED[((fbase+1)*32+lane)*4];
      s += *(f32x4*)&RED[((fbase+2)*32+lane)*4];
      u16* gp = gg + (size_t)((i+1)&1)*BG*H_;
      #pragma unroll
      for (int r = 0; r < 4; ++r){
        int row = lhalf*4 + r;                       // 0..7
        float hv = 0.9f*h0[r] + 0.1f*s[r] + 0.002f*NS[row*32 + w*16 + l15];
        h0[r] = hv;
        u16 gv = __builtin_bit_cast(u16, (__bf16)fast_tanh(hv));
        g_store_u16(gp + (size_t)row*H_ + c0 + w*16 + l15, (unsigned)gv);
      }
    }
    if (w == 2 && lane < 32 && i > 0){
      f32x4 s = co;
      s += *(f32x4*)&RED[((2*3+0)*32+lane)*4];
      s += *(f32x4*)&RED[((2*3+1)*32+lane)*4];
      s += *(f32x4*)&RED[((2*3+2)*32+lane)*4];
      if (l15 < 2){
        #pragma unroll
        for (int r = 0; r < 4; ++r){
          int row = lhalf*4 + r;
          out[((size_t)(grp*BG + row)*T_ + (i-1))*O_ + role*2 + l15] = s[r];
        }
      }
    }

    asm volatile("s_waitcnt vmcnt(0)" ::: "memory");   // g stores at coherence point
    __syncthreads();                                   // whole WG done with step i
    if (threadIdx.x == 0) sflag_store(myflag, (unsigned)(i+1));
  }

  // ---------- epilogue: out[T-1] = g_T @ wo ----------
  {
    const unsigned tgt = (unsigned)T_;
    int guard = 0;
    while (true){
      unsigned v = sflag_load(pollp);
      if (__all((int)(v >= tgt))) break;
      if (++guard > POLL_CAP) break;
    }
    const u16* ap = abase + (size_t)(T_ & 1)*BG*H_;
    u32x4 a[8];
    #pragma unroll
    for (int kt = 0; kt < 8; ++kt) g_load_frag(a[kt], ap + kt*32);
    asm volatile("s_waitcnt vmcnt(0)"
      : "+v"(a[0]),"+v"(a[1]),"+v"(a[2]),"+v"(a[3]),
        "+v"(a[4]),"+v"(a[5]),"+v"(a[6]),"+v"(a[7]));
    __builtin_amdgcn_sched_barrier(0);
    f32x4 oA={0.f,0.f,0.f,0.f}, oB={0.f,0.f,0.f,0.f};
    const int kb = w*8;
    #pragma unroll
    for (int kt = 0; kt < 8; ++kt){
      const int kg = kb + kt;
      bf16x8 wh = *(const bf16x8*)(B + WO_HI_E + wo_off + kg*32);
      bf16x8 wl = *(const bf16x8*)(B + WO_LO_E + wo_off + kg*32);
      bf16x8 av = BC(a[kt]);
      oA = MFMA(av, wh, oA, 0,0,0);  oB = MFMA(av, wl, oB, 0,0,0);
    }
    f32x4 co = oA + oB;
    if (lane < 32){
      if (w == 0) *(f32x4*)&RED[((2*3+0)*32+lane)*4] = co;
      if (w == 1) *(f32x4*)&RED[((2*3+1)*32+lane)*4] = co;
      if (w == 3) *(f32x4*)&RED[((2*3+2)*32+lane)*4] = co;
    }
    __syncthreads();
    if (w == 2 && lane < 32){
      f32x4 s = co;
      s += *(f32x4*)&RED[((2*3+0)*32+lane)*4];
      s += *(f32x4*)&RED[((2*3+1)*32+lane)*4];
      s += *(f32x4*)&RED[((2*3+2)*32+lane)*4];
      if (l15 < 2){
        #pragma unroll
        for (int r = 0; r < 4; ++r){
          int row = lhalf*4 + r;
          out[((size_t)(grp*BG + row)*T_ + (T_-1))*O_ + role*2 + l15] = s[r];
        }
      }
    }
  }
}

extern "C" void kernel_launch(void* const* d_in, const int* in_sizes, int n_in,
                              void* d_out, int out_size, void* d_ws, size_t ws_size,
                              hipStream_t stream){
  const float* x     = (const float*)d_in[0];
  const float* noise = (const float*)d_in[1];
  const float* wi    = (const float*)d_in[2];
  const float* wrec  = (const float*)d_in[3];
  const float* wo    = (const float*)d_in[4];
  float* out = (float*)d_out;

  if (ws_size < (size_t)WS_NEED) return;
  u16* gbuf = (u16*)d_ws;
  u16* sflags = (u16*)((char*)d_ws + STEPFLAG_OFF);

  hipMemsetAsync(d_ws, 0, WS_NEED, stream);   // zero g_0 + step flags

  hipFuncSetAttribute((const void*)rnn_kernel,
                      hipFuncAttributeMaxDynamicSharedMemorySize, LDS_BYTES);

  void* args[] = {(void*)&x, (void*)&noise, (void*)&wi, (void*)&wrec, (void*)&wo,
                  (void*)&out, (void*)&gbuf, (void*)&sflags};
  hipLaunchCooperativeKernel((const void*)rnn_kernel, dim3(NWG), dim3(256),
                             args, LDS_BYTES, stream);
}

// Round 6
// 3036.114 us; speedup vs baseline: 1.8885x; 1.1029x over previous
//
#include <hip/hip_runtime.h>
#include <hip/hip_bf16.h>

// Leaky tanh RNN, persistent cooperative kernel (round 6: 2-chain interleave).
// 8 chains (batch-groups of 8). 128 WGs; WG (pid,role) owns col-slice
// [32*role, 32*role+32) of wrec/wi/wo for chains A=2*pid, B=2*pid+1 (weights in
// LDS, shared by both chains). Per half-phase: compute chain C step i (MFMAs,
// LDS reduce, h-update, publish g_{i+1}), while chain D's next step is
// prefetched in the same phase (early flag poll, g A-frag loads, x@wi MFMAs,
// noise staging) so D's latency hides under C's compute and vice versa.
// Comm protocol unchanged from proven round 5: all g/flag ops sc0 sc1 (system
// scope / MALL coherence point), producer drains stores (vmcnt0) before flag.
// In-loop barriers are raw lgkmcnt(0)+s_barrier so prefetch loads stay in
// flight across them. Per-producer-wave flags: 64 per group (role*2 + wave).

#define T_ 512
#define I_ 128
#define H_ 1024
#define O_ 64
#define NWG 128
#define POLL_CAP (1<<17)

// workspace
#define GBUF_BYTES (8*2*8*H_*2)          // 262144
#define STEPFLAG_OFF GBUF_BYTES          // u16[8][64] = 1024 B
#define WS_NEED (GBUF_BYTES + 1024)      // 263168 (same as proven R5 footprint)

// LDS (bf16 element offsets for weights; byte offsets for f32 regions)
#define WREC_HI_E 0
#define WREC_LO_E 32768
#define WI_HI_E   65536
#define WI_LO_E   69632
#define WO_HI_E   73728
#define WO_LO_E   75776
#define RED_OFF_B   155648   // 9 slots * 32 lanes * 16B
#define NSA_OFF_B   160256   // 8*32 f32
#define NSB_OFF_B   161280
#define LDS_BYTES   162304

typedef __bf16 bf16x8 __attribute__((ext_vector_type(8)));
typedef float f32x4 __attribute__((ext_vector_type(4)));
typedef unsigned u32x4 __attribute__((ext_vector_type(4)));
typedef unsigned short u16;

__device__ __forceinline__ float fast_tanh(float v){
  float cx = fminf(fmaxf(v, -14.f), 14.f);
  float e = __builtin_amdgcn_exp2f(cx * 2.8853900817779268f);
  return 1.f - 2.f * __builtin_amdgcn_rcpf(e + 1.f);
}

// ---- system-scope comm primitives (proven in R5) ----
__device__ __forceinline__ void flag_issue(unsigned& v, const u16* p){
  asm volatile("global_load_ushort %0, %1, off sc0 sc1" : "=v"(v) : "v"(p));
}
__device__ __forceinline__ unsigned sflag_load(const u16* p){
  unsigned v;
  asm volatile("global_load_ushort %0, %1, off sc0 sc1\n\ts_waitcnt vmcnt(0)"
               : "=v"(v) : "v"(p) : "memory");
  return v;
}
__device__ __forceinline__ void sflag_store(u16* p, unsigned v){
  asm volatile("global_store_short %0, %1, off sc0 sc1" :: "v"(p), "v"(v) : "memory");
}
__device__ __forceinline__ void g_load_frag(u32x4& d, const u16* p){
  asm volatile("global_load_dwordx4 %0, %1, off sc0 sc1" : "=v"(d) : "v"(p) : "memory");
}
__device__ __forceinline__ void g_store_u16(u16* p, unsigned v){
  asm volatile("global_store_short %0, %1, off sc0 sc1" :: "v"(p), "v"(v) : "memory");
}
// plain cached input loads (x / noise), asm so vmcnt bookkeeping stays manual
__device__ __forceinline__ void gl_f32x4(f32x4& d, const float* p){
  asm volatile("global_load_dwordx4 %0, %1, off" : "=v"(d) : "v"(p));
}
__device__ __forceinline__ void gl_f32(float& d, const float* p){
  asm volatile("global_load_dword %0, %1, off" : "=v"(d) : "v"(p));
}
// execution barrier + LDS ordering only: does NOT drain vmcnt (prefetch stays in flight)
__device__ __forceinline__ void barrier_lds(){
  asm volatile("s_waitcnt lgkmcnt(0)\n\ts_barrier" ::: "memory");
}

// [K x 32] col-slice of row-major [K x ld] fp32 -> LDS split bf16 (hi+lo),
// pre-swizzled into MFMA B-frag order (verified rounds 1-5).
__device__ void load_slice(const float* __restrict__ Wg, int ld, int c0, int K,
                           __bf16* hi, __bf16* lo){
  for (int idx = threadIdx.x; idx < K*32; idx += 256){
    int k = idx >> 5, c = idx & 31;
    float v = Wg[(size_t)k*ld + c0 + c];
    __bf16 h = (__bf16)v;
    __bf16 l = (__bf16)(v - (float)h);
    int kt = k >> 5, kin = k & 31, lg = kin >> 3, j = kin & 7;
    int off = (((kt*2 + (c>>4))*64 + (lg*16 + (c&15))) << 3) + j;
    hi[off] = h; lo[off] = l;
  }
}

#define MFMA __builtin_amdgcn_mfma_f32_16x16x32_bf16
#define BC(u) __builtin_bit_cast(bf16x8, u)

struct Chain {
  u32x4 a[8];          // prefetched g A-frags
  f32x4 h0, xA, xB;    // h state, x@wi seeds (hi/lo passes)
  u16 *gg, *gf;
  const u16 *ab;       // per-lane A-frag base into gg
  const float *xb, *nb;
  float *ob;
  float *NS;           // LDS noise stage for this chain
};

// compute chain C step i; prepare chain D step j (j==T_ -> g loads only)
__device__ __forceinline__ void do_half(
    Chain& C, Chain& D, int i, int j,
    __bf16* B, float* RED,
    int lane, int w, int lhalf, int l15, int bf, int wo_off, int c0, int role)
{
  // 1: complete C's g_i A-frag loads (issued during previous half)
  asm volatile("s_waitcnt vmcnt(0)"
    : "+v"(C.a[0]),"+v"(C.a[1]),"+v"(C.a[2]),"+v"(C.a[3]),
      "+v"(C.a[4]),"+v"(C.a[5]),"+v"(C.a[6]),"+v"(C.a[7]) :: "memory");
  __builtin_amdgcn_sched_barrier(0);

  // 1.5: early-issue D's inputs + first flag-poll read (latency hides under C)
  f32x4 xv0,xv1,xv2,xv3,xv4,xv5,xv6,xv7;
  float n0,n1,n2,n3;
  if (j < T_){
    if (w < 2){
      const float* xp = D.xb + ((size_t)(l15 & 7)*T_ + (size_t)j)*I_ + lhalf*8;
      gl_f32x4(xv0, xp);      gl_f32x4(xv1, xp+4);
      gl_f32x4(xv2, xp+32);   gl_f32x4(xv3, xp+36);
      gl_f32x4(xv4, xp+64);   gl_f32x4(xv5, xp+68);
      gl_f32x4(xv6, xp+96);   gl_f32x4(xv7, xp+100);
    } else if (w == 3){
      const int b0 = lane >> 5, cc = lane & 31;
      gl_f32(n0, D.nb + ((size_t)(b0+0)*T_ + j)*H_ + c0 + cc);
      gl_f32(n1, D.nb + ((size_t)(b0+2)*T_ + j)*H_ + c0 + cc);
      gl_f32(n2, D.nb + ((size_t)(b0+4)*T_ + j)*H_ + c0 + cc);
      gl_f32(n3, D.nb + ((size_t)(b0+6)*T_ + j)*H_ + c0 + cc);
    }
  }
  unsigned pv; flag_issue(pv, D.gf + lane);

  // 2: MFMAs for C (wrec hi/lo both halves of slice + wo hi/lo)
  f32x4 c0A={0.f,0.f,0.f,0.f}, c0B={0.f,0.f,0.f,0.f};
  f32x4 c1A={0.f,0.f,0.f,0.f}, c1B={0.f,0.f,0.f,0.f};
  f32x4 oA ={0.f,0.f,0.f,0.f}, oB ={0.f,0.f,0.f,0.f};
  if (w == 0){ c0A = C.xA; c0B = C.xB; }
  if (w == 1){ c1A = C.xA; c1B = C.xB; }
  const int kb = w*8;
  #pragma unroll
  for (int kt = 0; kt < 8; ++kt){
    const int kg = kb + kt;
    bf16x8 bh0 = *(const bf16x8*)(B + WREC_HI_E + kg*1024 + bf);
    bf16x8 bl0 = *(const bf16x8*)(B + WREC_LO_E + kg*1024 + bf);
    bf16x8 bh1 = *(const bf16x8*)(B + WREC_HI_E + kg*1024 + 512 + bf);
    bf16x8 bl1 = *(const bf16x8*)(B + WREC_LO_E + kg*1024 + 512 + bf);
    bf16x8 wh  = *(const bf16x8*)(B + WO_HI_E + wo_off + kg*32);
    bf16x8 wl  = *(const bf16x8*)(B + WO_LO_E + wo_off + kg*32);
    bf16x8 av = BC(C.a[kt]);
    c0A = MFMA(av, bh0, c0A, 0,0,0);  c0B = MFMA(av, bl0, c0B, 0,0,0);
    c1A = MFMA(av, bh1, c1A, 0,0,0);  c1B = MFMA(av, bl1, c1B, 0,0,0);
    oA  = MFMA(av, wh,  oA,  0,0,0);  oB  = MFMA(av, wl,  oB,  0,0,0);
  }
  f32x4 cn0 = c0A + c0B, cn1 = c1A + c1B, co = oA + oB;

  // 3: cross-wave partials
  if (lane < 32){
    if (w == 0){ *(f32x4*)&RED[((1*3+0)*32+lane)*4] = cn1; *(f32x4*)&RED[((2*3+0)*32+lane)*4] = co; }
    if (w == 1){ *(f32x4*)&RED[((0*3+0)*32+lane)*4] = cn0; *(f32x4*)&RED[((2*3+1)*32+lane)*4] = co; }
    if (w == 2){ *(f32x4*)&RED[((0*3+1)*32+lane)*4] = cn0; *(f32x4*)&RED[((1*3+1)*32+lane)*4] = cn1; }
    if (w == 3){ *(f32x4*)&RED[((0*3+2)*32+lane)*4] = cn0; *(f32x4*)&RED[((1*3+2)*32+lane)*4] = cn1; *(f32x4*)&RED[((2*3+2)*32+lane)*4] = co; }
  }
  barrier_lds();

  // 4: owners reduce + h update + store g_{i+1}; w2 writes out[i-1]
  if (w < 2 && lane < 32){
    const int fbase = w ? 3 : 0;
    f32x4 s = w ? cn1 : cn0;
    s += *(f32x4*)&RED[((fbase+0)*32+lane)*4];
    s += *(f32x4*)&RED[((fbase+1)*32+lane)*4];
    s += *(f32x4*)&RED[((fbase+2)*32+lane)*4];
    u16* gp = C.gg + (size_t)((i+1)&1)*(8*H_);
    #pragma unroll
    for (int r = 0; r < 4; ++r){
      int row = lhalf*4 + r;
      float hv = 0.9f*C.h0[r] + 0.1f*s[r] + 0.002f*C.NS[row*32 + w*16 + l15];
      C.h0[r] = hv;
      u16 gv = __builtin_bit_cast(u16, (__bf16)fast_tanh(hv));
      g_store_u16(gp + (size_t)row*H_ + c0 + w*16 + l15, (unsigned)gv);
    }
  }
  if (w == 2 && lane < 32 && i > 0){
    f32x4 s = co;
    s += *(f32x4*)&RED[((2*3+0)*32+lane)*4];
    s += *(f32x4*)&RED[((2*3+1)*32+lane)*4];
    s += *(f32x4*)&RED[((2*3+2)*32+lane)*4];
    if (l15 < 2){
      #pragma unroll
      for (int r = 0; r < 4; ++r){
        int row = lhalf*4 + r;
        C.ob[((size_t)row*T_ + (i-1))*O_ + role*2 + l15] = s[r];
      }
    }
  }

  // drain: g/out stores reach coherence point; pv + early inputs complete
  if (j < T_ && w < 2){
    asm volatile("s_waitcnt vmcnt(0)"
      : "+v"(pv),"+v"(xv0),"+v"(xv1),"+v"(xv2),"+v"(xv3),
        "+v"(xv4),"+v"(xv5),"+v"(xv6),"+v"(xv7) :: "memory");
  } else if (j < T_ && w == 3){
    asm volatile("s_waitcnt vmcnt(0)"
      : "+v"(pv),"+v"(n0),"+v"(n1),"+v"(n2),"+v"(n3) :: "memory");
  } else {
    asm volatile("s_waitcnt vmcnt(0)" : "+v"(pv) :: "memory");
  }
  __builtin_amdgcn_sched_barrier(0);

  // publish this wave's flag (producer waves only)
  if (w < 2 && lane == 0) sflag_store(C.gf + role*2 + w, (unsigned)(i+1));

  // 5: confirm D flags (early read usually suffices), issue D's g_j loads
  {
    const unsigned tgt = (unsigned)j;
    if (!__all((int)(pv >= tgt))){
      int guard = 0;
      while (true){
        unsigned v = sflag_load(D.gf + lane);
        if (__all((int)(v >= tgt))) break;
        if (++guard > POLL_CAP) break;   // bail: wrong answer beats a hang
      }
    }
  }
  {
    const u16* ap = D.ab + (size_t)(j & 1)*(8*H_);
    #pragma unroll
    for (int kt = 0; kt < 8; ++kt) g_load_frag(D.a[kt], ap + kt*32);
  }
  if (j < T_){
    if (w < 2){
      f32x4 nxA = {0.f,0.f,0.f,0.f}, nxB = {0.f,0.f,0.f,0.f};
      #pragma unroll
      for (int kt = 0; kt < 4; ++kt){
        f32x4 v0 = (kt==0)?xv0:(kt==1)?xv2:(kt==2)?xv4:xv6;
        f32x4 v1 = (kt==0)?xv1:(kt==1)?xv3:(kt==2)?xv5:xv7;
        bf16x8 xh, xl;
        #pragma unroll
        for (int jj = 0; jj < 4; ++jj){
          float aa = v0[jj], bb = v1[jj];
          __bf16 ah = (__bf16)aa, bh2 = (__bf16)bb;
          xh[jj] = ah; xh[jj+4] = bh2;
          xl[jj] = (__bf16)(aa - (float)ah); xl[jj+4] = (__bf16)(bb - (float)bh2);
        }
        bf16x8 wih = *(const bf16x8*)(B + WI_HI_E + kt*1024 + w*512 + bf);
        bf16x8 wil = *(const bf16x8*)(B + WI_LO_E + kt*1024 + w*512 + bf);
        nxA = MFMA(xh, wih, nxA, 0,0,0);
        nxB = MFMA(xl, wih, nxB, 0,0,0);
        nxA = MFMA(xh, wil, nxA, 0,0,0);
      }
      D.xA = nxA; D.xB = nxB;
    } else if (w == 3){
      const int b0 = lane >> 5, cc = lane & 31;
      D.NS[(b0+0)*32 + cc] = n0;
      D.NS[(b0+2)*32 + cc] = n1;
      D.NS[(b0+4)*32 + cc] = n2;
      D.NS[(b0+6)*32 + cc] = n3;
    }
  }

  // 6: end-of-half barrier (RED reuse + NS visibility)
  barrier_lds();
}

// prologue prep of chain D step 0 (flags trivially satisfied; g_0 is zeroed)
__device__ __forceinline__ void prep0(Chain& D, __bf16* B,
    int lane, int w, int lhalf, int l15, int bf, int c0)
{
  f32x4 xv0,xv1,xv2,xv3,xv4,xv5,xv6,xv7;
  float n0,n1,n2,n3;
  if (w < 2){
    const float* xp = D.xb + (size_t)(l15 & 7)*T_*I_ + lhalf*8;
    gl_f32x4(xv0, xp);      gl_f32x4(xv1, xp+4);
    gl_f32x4(xv2, xp+32);   gl_f32x4(xv3, xp+36);
    gl_f32x4(xv4, xp+64);   gl_f32x4(xv5, xp+68);
    gl_f32x4(xv6, xp+96);   gl_f32x4(xv7, xp+100);
    asm volatile("s_waitcnt vmcnt(0)"
      : "+v"(xv0),"+v"(xv1),"+v"(xv2),"+v"(xv3),
        "+v"(xv4),"+v"(xv5),"+v"(xv6),"+v"(xv7) :: "memory");
  } else if (w == 3){
    const int b0 = lane >> 5, cc = lane & 31;
    gl_f32(n0, D.nb + (size_t)(b0+0)*T_*H_ + c0 + cc);
    gl_f32(n1, D.nb + (size_t)(b0+2)*T_*H_ + c0 + cc);
    gl_f32(n2, D.nb + (size_t)(b0+4)*T_*H_ + c0 + cc);
    gl_f32(n3, D.nb + (size_t)(b0+6)*T_*H_ + c0 + cc);
    asm volatile("s_waitcnt vmcnt(0)"
      : "+v"(n0),"+v"(n1),"+v"(n2),"+v"(n3) :: "memory");
  }
  __builtin_amdgcn_sched_barrier(0);
  #pragma unroll
  for (int kt = 0; kt < 8; ++kt) g_load_frag(D.a[kt], D.ab + kt*32);
  if (w < 2){
    f32x4 nxA = {0.f,0.f,0.f,0.f}, nxB = {0.f,0.f,0.f,0.f};
    #pragma unroll
    for (int kt = 0; kt < 4; ++kt){
      f32x4 v0 = (kt==0)?xv0:(kt==1)?xv2:(kt==2)?xv4:xv6;
      f32x4 v1 = (kt==0)?xv1:(kt==1)?xv3:(kt==2)?xv5:xv7;
      bf16x8 xh, xl;
      #pragma unroll
      for (int jj = 0; jj < 4; ++jj){
        float aa = v0[jj], bb = v1[jj];
        __bf16 ah = (__bf16)aa, bh2 = (__bf16)bb;
        xh[jj] = ah; xh[jj+4] = bh2;
        xl[jj] = (__bf16)(aa - (float)ah); xl[jj+4] = (__bf16)(bb - (float)bh2);
      }
      bf16x8 wih = *(const bf16x8*)(B + WI_HI_E + kt*1024 + w*512 + bf);
      bf16x8 wil = *(const bf16x8*)(B + WI_LO_E + kt*1024 + w*512 + bf);
      nxA = MFMA(xh, wih, nxA, 0,0,0);
      nxB = MFMA(xl, wih, nxB, 0,0,0);
      nxA = MFMA(xh, wil, nxA, 0,0,0);
    }
    D.xA = nxA; D.xB = nxB;
  } else if (w == 3){
    const int b0 = lane >> 5, cc = lane & 31;
    D.NS[(b0+0)*32 + cc] = n0;
    D.NS[(b0+2)*32 + cc] = n1;
    D.NS[(b0+4)*32 + cc] = n2;
    D.NS[(b0+6)*32 + cc] = n3;
  }
  barrier_lds();
}

// epilogue: out[T-1] = g_T @ wo for chain C (C.a holds g_T frags)
__device__ __forceinline__ void epi(Chain& C, __bf16* B, float* RED,
    int lane, int w, int lhalf, int l15, int bf, int wo_off, int role)
{
  asm volatile("s_waitcnt vmcnt(0)"
    : "+v"(C.a[0]),"+v"(C.a[1]),"+v"(C.a[2]),"+v"(C.a[3]),
      "+v"(C.a[4]),"+v"(C.a[5]),"+v"(C.a[6]),"+v"(C.a[7]) :: "memory");
  __builtin_amdgcn_sched_barrier(0);
  f32x4 oA={0.f,0.f,0.f,0.f}, oB={0.f,0.f,0.f,0.f};
  const int kb = w*8;
  #pragma unroll
  for (int kt = 0; kt < 8; ++kt){
    const int kg = kb + kt;
    bf16x8 wh = *(const bf16x8*)(B + WO_HI_E + wo_off + kg*32);
    bf16x8 wl = *(const bf16x8*)(B + WO_LO_E + wo_off + kg*32);
    bf16x8 av = BC(C.a[kt]);
    oA = MFMA(av, wh, oA, 0,0,0);  oB = MFMA(av, wl, oB, 0,0,0);
  }
  f32x4 co = oA + oB;
  barrier_lds();   // prior RED consumers done
  if (lane < 32){
    if (w == 0) *(f32x4*)&RED[((2*3+0)*32+lane)*4] = co;
    if (w == 1) *(f32x4*)&RED[((2*3+1)*32+lane)*4] = co;
    if (w == 3) *(f32x4*)&RED[((2*3+2)*32+lane)*4] = co;
  }
  barrier_lds();
  if (w == 2 && lane < 32){
    f32x4 s = co;
    s += *(f32x4*)&RED[((2*3+0)*32+lane)*4];
    s += *(f32x4*)&RED[((2*3+1)*32+lane)*4];
    s += *(f32x4*)&RED[((2*3+2)*32+lane)*4];
    if (l15 < 2){
      #pragma unroll
      for (int r = 0; r < 4; ++r){
        int row = lhalf*4 + r;
        C.ob[((size_t)row*T_ + (T_-1))*O_ + role*2 + l15] = s[r];
      }
    }
  }
}

extern "C" __global__ __launch_bounds__(256, 1)
void rnn_kernel(const float* __restrict__ x, const float* __restrict__ noise,
                const float* __restrict__ wi, const float* __restrict__ wrec,
                const float* __restrict__ wo, float* __restrict__ out,
                u16* __restrict__ gbuf, u16* __restrict__ sflags)
{
  extern __shared__ char smem[];
  __bf16* B = (__bf16*)smem;
  float* RED = (float*)(smem + RED_OFF_B);

  const int pid  = blockIdx.x >> 5;
  const int role = blockIdx.x & 31;
  const int c0 = role * 32;

  load_slice(wrec, H_, c0, H_, B + WREC_HI_E, B + WREC_LO_E);
  load_slice(wi,   H_, c0, I_, B + WI_HI_E,  B + WI_LO_E);
  for (int idx = threadIdx.x; idx < 2*H_; idx += 256){
    int col = idx >> 10, k = idx & (H_-1);
    float v = wo[(size_t)k*O_ + role*2 + col];
    __bf16 hh = (__bf16)v;
    B[WO_HI_E + col*H_ + k] = hh;
    B[WO_LO_E + col*H_ + k] = (__bf16)(v - (float)hh);
  }
  __syncthreads();

  const int lane = threadIdx.x & 63;
  const int w    = threadIdx.x >> 6;
  const int lhalf = lane >> 4;
  const int l15   = lane & 15;
  const int bf = lane * 8;
  const int wo_off = (l15 & 1)*1024 + lhalf*8;

  Chain A, Bc;
  const int gA = pid*2, gB = pid*2+1;
  A.gg  = gbuf + gA*(2*8*H_);   A.gf  = sflags + gA*64;
  Bc.gg = gbuf + gB*(2*8*H_);   Bc.gf = sflags + gB*64;
  A.ab  = A.gg  + (size_t)(lane & 7)*H_ + w*256 + lhalf*8;
  Bc.ab = Bc.gg + (size_t)(lane & 7)*H_ + w*256 + lhalf*8;
  A.xb  = x + (size_t)(gA*8)*T_*I_;     Bc.xb = x + (size_t)(gB*8)*T_*I_;
  A.nb  = noise + (size_t)(gA*8)*T_*H_; Bc.nb = noise + (size_t)(gB*8)*T_*H_;
  A.ob  = out + (size_t)(gA*8)*T_*O_;   Bc.ob = out + (size_t)(gB*8)*T_*O_;
  A.NS  = (float*)(smem + NSA_OFF_B);   Bc.NS = (float*)(smem + NSB_OFF_B);
  A.h0  = (f32x4){0.f,0.f,0.f,0.f};     Bc.h0 = (f32x4){0.f,0.f,0.f,0.f};
  A.xA  = (f32x4){0.f,0.f,0.f,0.f};     A.xB  = (f32x4){0.f,0.f,0.f,0.f};
  Bc.xA = (f32x4){0.f,0.f,0.f,0.f};     Bc.xB = (f32x4){0.f,0.f,0.f,0.f};

  prep0(A, B, lane, w, lhalf, l15, bf, c0);

  for (int i = 0; i < T_; ++i){
    do_half(A,  Bc, i, i,   B, RED, lane, w, lhalf, l15, bf, wo_off, c0, role);
    do_half(Bc, A,  i, i+1, B, RED, lane, w, lhalf, l15, bf, wo_off, c0, role);
  }

  epi(A, B, RED, lane, w, lhalf, l15, bf, wo_off, role);
  { // fetch B's g_T (not prefetched) and finish
    int guard = 0;
    while (true){
      unsigned v = sflag_load(Bc.gf + lane);
      if (__all((int)(v >= (unsigned)T_))) break;
      if (++guard > POLL_CAP) break;
    }
    #pragma unroll
    for (int kt = 0; kt < 8; ++kt) g_load_frag(Bc.a[kt], Bc.ab + kt*32); // parity T&1==0
  }
  epi(Bc, B, RED, lane, w, lhalf, l15, bf, wo_off, role);
}

extern "C" void kernel_launch(void* const* d_in, const int* in_sizes, int n_in,
                              void* d_out, int out_size, void* d_ws, size_t ws_size,
                              hipStream_t stream){
  const float* x     = (const float*)d_in[0];
  const float* noise = (const float*)d_in[1];
  const float* wi    = (const float*)d_in[2];
  const float* wrec  = (const float*)d_in[3];
  const float* wo    = (const float*)d_in[4];
  float* out = (float*)d_out;

  if (ws_size < (size_t)WS_NEED) return;
  u16* gbuf = (u16*)d_ws;
  u16* sflags = (u16*)((char*)d_ws + STEPFLAG_OFF);

  hipMemsetAsync(d_ws, 0, WS_NEED, stream);   // zero g_0 + flags

  hipFuncSetAttribute((const void*)rnn_kernel,
                      hipFuncAttributeMaxDynamicSharedMemorySize, LDS_BYTES);

  void* args[] = {(void*)&x, (void*)&noise, (void*)&wi, (void*)&wrec, (void*)&wo,
                  (void*)&out, (void*)&gbuf, (void*)&sflags};
  hipLaunchCooperativeKernel((const void*)rnn_kernel, dim3(NWG), dim3(256),
                             args, LDS_BYTES, stream);
}